// Round 4
// baseline (815.131 us; speedup 1.0000x reference)
//
#include <hip/hip_runtime.h>
#include <math.h>

typedef _Float16 f16x8 __attribute__((ext_vector_type(8)));
typedef float    f32x4 __attribute__((ext_vector_type(4)));
typedef __fp16   fp16x2 __attribute__((ext_vector_type(2)));

#define B_TOT 2048
#define LSEQ  512
#define LOG2E 1.44269504088896f
#define LN2   0.69314718055995f

#define MFMA16(A, B, C) __builtin_amdgcn_mfma_f32_16x16x32_f16((A), (B), (C), 0, 0, 0)

__device__ __forceinline__ unsigned int pkrtz(float a, float b) {
    fp16x2 p = __builtin_amdgcn_cvt_pkrtz(a, b);
    return __builtin_bit_cast(unsigned int, p);
}
__device__ __forceinline__ float f16lo(unsigned int u) {
    return (float)__builtin_bit_cast(fp16x2, u)[0];
}
__device__ __forceinline__ float f16hi(unsigned int u) {
    return (float)__builtin_bit_cast(fp16x2, u)[1];
}

// One wave per 2 samples. The wave computes ALL 256 gate rows itself
// (16 tiles x 2 K-halves = 32 MFMAs/step, B cols = 2 samples duplicated 8x).
// h-exchange is a same-wave LDS round-trip: NO barrier anywhere in the kernel.
// Gate-row rho = 64*g + f; tile t = 4*g + c covers rho in [16t,16t+16);
// lane (n,q) owns features f = 16c + 4q + 2p + {0,1}, sample ns = n&1,
// where k = n>>1, c = k>>1, p = k&1. Needed acc slots: acc[4g+c][2p+j].
__global__ __launch_bounds__(256, 1)
void lstm_v17_kernel(const int* __restrict__ s,
                     const float* __restrict__ W0, const float* __restrict__ b0,
                     const float* __restrict__ Wi, const float* __restrict__ Wh,
                     const float* __restrict__ bh, const float* __restrict__ Wa,
                     const float* __restrict__ ba, const float* __restrict__ Wp,
                     const float* __restrict__ bp, float* __restrict__ out)
{
    const int tid  = threadIdx.x;
    const int w    = tid >> 6;     // wave in block (independent; no barriers)
    const int lane = tid & 63;
    const int n    = lane & 15;    // MFMA column; sample = n&1, 8 col-copies
    const int q    = lane >> 4;
    const int ns   = n & 1;
    const int kcpy = n >> 1;       // copy index 0..7
    const int c    = kcpy >> 1;    // feature chunk 0..3
    const int p    = kcpy & 1;     // sub-pair 0..1
    const int b0s  = blockIdx.x * 8 + w * 2;   // 2 samples per wave

    __shared__ __align__(16) unsigned int HWX[4 * 64];   // 1 KB  h exchange
    __shared__ unsigned char TOKW[4][LSEQ + 4];          // 2 KB  2-bit token masks
    __shared__ _Float16 DBUF[4][LSEQ][2];                // 8 KB  logit diffs

    // ---- stage tokens (per wave, coalesced in t) ----
    #pragma unroll
    for (int j = 0; j < 8; ++j) {
        int t = lane + 64 * j;
        int s0 = s[(b0s + 0) * LSEQ + t];
        int s1 = s[(b0s + 1) * LSEQ + t];
        TOKW[w][t] = (unsigned char)(s0 | (s1 << 1));
    }
    if (lane == 0) TOKW[w][LSEQ] = 0;

    // ---- presums p0/dp for ALL 16 tiles (fp32, safe precision) ----
    f32x4 p0q[16], dpq[16];
    {
        f32x4 A0[16], A1[16];
        #pragma unroll
        for (int t = 0; t < 16; ++t)
            #pragma unroll
            for (int r = 0; r < 4; ++r) {
                float bb = bh[16 * t + 4 * q + r];
                A0[t][r] = bb; A1[t][r] = bb;
            }
        #pragma unroll 2
        for (int f = 0; f < 64; ++f) {
            float wb0 = W0[f]      + b0[f];
            float wb1 = W0[64 + f] + b0[f];
            #pragma unroll
            for (int t = 0; t < 16; ++t) {
                const float4 wi4 = *(const float4*)&Wi[f * 256 + 16 * t + 4 * q];
                #pragma unroll
                for (int r = 0; r < 4; ++r) {
                    float wv = (&wi4.x)[r];
                    A0[t][r] = fmaf(wb0, wv, A0[t][r]);
                    A1[t][r] = fmaf(wb1, wv, A1[t][r]);
                }
            }
        }
        #pragma unroll
        for (int t = 0; t < 16; ++t) {
            const float sc = ((t >> 2) == 2) ? (2.0f * LOG2E) : (-LOG2E);
            #pragma unroll
            for (int r = 0; r < 4; ++r) {
                p0q[t][r] = A0[t][r] * sc;
                dpq[t][r] = (A1[t][r] - A0[t][r]) * sc;
            }
        }
    }

    // ---- A-frags: scaled Wh^T for all 16 tiles ----
    f16x8 awh[16][2];
    #pragma unroll
    for (int t = 0; t < 16; ++t) {
        const float sc = ((t >> 2) == 2) ? (2.0f * LOG2E) : (-LOG2E);
        const int col = 16 * t + n;
        #pragma unroll
        for (int h = 0; h < 2; ++h)
            #pragma unroll
            for (int j = 0; j < 8; ++j)
                awh[t][h][j] = (_Float16)(Wh[(32 * h + 8 * q + j) * 256 + col] * sc);
    }
    // d-GEMM A-frag: row 0 = Wa[:,1]-Wa[:,0]
    f16x8 awd[2];
    #pragma unroll
    for (int h = 0; h < 2; ++h)
        #pragma unroll
        for (int j = 0; j < 8; ++j) {
            int kx = 32 * h + 8 * q + j;
            awd[h][j] = (_Float16)((n == 0) ? (Wa[2 * kx + 1] - Wa[2 * kx]) : 0.0f);
        }
    const float dba = ba[1] - ba[0];

    // ---- LDS dword addresses: write one packed pair, read 2x b128 ----
    const int wA  = w * 64 + 32 * ns + 8 * c + 2 * q + p;   // dword = 32*ns + f/2
    const int rA0 = w * 64 + 32 * ns + 4 * q;               // features 8q..8q+7

    float h2[2] = {0.f, 0.f}, c2[2] = {0.f, 0.f};
    float selc = 0.f;   // token bit for C-build (pad token 0 at v=0)

    for (int v = 0; v <= LSEQ; ++v) {
        // publish h_{v-1} (same-wave exchange; lgkmcnt ordering, no barrier)
        HWX[wA] = pkrtz(h2[0], h2[1]);
        const unsigned int tk = TOKW[w][v];            // tokens[v], for next iter
        const uint4 r0 = *(const uint4*)&HWX[rA0];
        const uint4 r1 = *(const uint4*)&HWX[rA0 + 16];
        const f16x8 bf0 = __builtin_bit_cast(f16x8, r0);
        const f16x8 bf1 = __builtin_bit_cast(f16x8, r1);

        // gates GEMM: C built just-in-time (keeps live regs down)
        const f32x4 sel4 = {selc, selc, selc, selc};
        f32x4 acc[16];
        #pragma unroll
        for (int t = 0; t < 16; ++t)
            acc[t] = MFMA16(awh[t][0], bf0, dpq[t] * sel4 + p0q[t]);
        #pragma unroll
        for (int t = 0; t < 16; ++t)
            acc[t] = MFMA16(awh[t][1], bf1, acc[t]);

        // logit-diff for t = v-1
        f32x4 da = {dba, dba, dba, dba};
        da = MFMA16(awd[0], bf0, da);
        da = MFMA16(awd[1], bf1, da);

        selc = (float)((tk >> ns) & 1u);

        // select this lane's 8 gate values: acc[4g+c][2p+j]
        float gl[4], gh[4];
        #pragma unroll
        for (int g = 0; g < 4; ++g) {
            float pl0 = p ? acc[4*g+0][2] : acc[4*g+0][0];
            float pl1 = p ? acc[4*g+1][2] : acc[4*g+1][0];
            float pl2 = p ? acc[4*g+2][2] : acc[4*g+2][0];
            float pl3 = p ? acc[4*g+3][2] : acc[4*g+3][0];
            float ph0 = p ? acc[4*g+0][3] : acc[4*g+0][1];
            float ph1 = p ? acc[4*g+1][3] : acc[4*g+1][1];
            float ph2 = p ? acc[4*g+2][3] : acc[4*g+2][1];
            float ph3 = p ? acc[4*g+3][3] : acc[4*g+3][1];
            float la = (c & 1) ? pl1 : pl0;
            float lb = (c & 1) ? pl3 : pl2;
            gl[g] = (c & 2) ? lb : la;
            float ha = (c & 1) ? ph1 : ph0;
            float hb = (c & 1) ? ph3 : ph2;
            gh[g] = (c & 2) ? hb : ha;
        }

        // activations: 5 exp2 + 2 rcp per cell, 2 cells/lane
        #pragma unroll
        for (int jj = 0; jj < 2; ++jj) {
            float gi = jj ? gh[0] : gl[0];
            float gf = jj ? gh[1] : gl[1];
            float gg = jj ? gh[2] : gl[2];
            float go = jj ? gh[3] : gl[3];
            float ei = __builtin_amdgcn_exp2f(gi);                // e^{-i}
            float ef = __builtin_amdgcn_exp2f(gf);                // e^{-f}
            float eg = __builtin_amdgcn_exp2f(gg);                // e^{2g}
            float eo = __builtin_amdgcn_exp2f(go);                // e^{-o}
            float P  = (1.0f + ei) * (eg + 1.0f);
            float F  = 1.0f + ef;
            float R2 = __builtin_amdgcn_rcpf(P * F);
            float cn = fmaf(c2[jj] * P, R2, (eg - 1.0f) * F * R2);
            c2[jj] = cn;
            float ec = __builtin_amdgcn_exp2f(fminf(cn * (2.0f * LOG2E), 60.f));
            float Ro = __builtin_amdgcn_rcpf((1.0f + eo) * (ec + 1.0f));
            h2[jj] = (ec - 1.0f) * Ro;
        }

        if (v >= 1 && lane < 2) DBUF[w][v - 1][lane] = (_Float16)da[0];
    }

    // ---- amp post-pass (same wave wrote DBUF; lgkmcnt only) ----
    {
        float aa0 = 0.f, aa1 = 0.f;
        #pragma unroll 2
        for (int j = 0; j < 8; ++j) {
            int t = lane + 64 * j;
            unsigned int dd = *(const unsigned int*)&DBUF[w][t][0];
            float d0 = f16lo(dd), d1 = f16hi(dd);
            unsigned int tk = TOKW[w][t];
            float x0 = (tk & 1u) ? -d0 : d0;
            float x1 = (tk & 2u) ? -d1 : d1;
            float e0 = __builtin_amdgcn_exp2f(-fabsf(x0) * LOG2E);
            float e1 = __builtin_amdgcn_exp2f(-fabsf(x1) * LOG2E);
            aa0 += fmaxf(x0, 0.f) + __builtin_amdgcn_logf(1.0f + e0) * LN2;
            aa1 += fmaxf(x1, 0.f) + __builtin_amdgcn_logf(1.0f + e1) * LN2;
        }
        #pragma unroll
        for (int m = 1; m < 64; m <<= 1) {
            aa0 += __shfl_xor(aa0, m, 64);
            aa1 += __shfl_xor(aa1, m, 64);
        }
        if (lane == 0) {
            out[b0s + 0] = -0.5f * aa0;            // planar real
            out[b0s + 1] = -0.5f * aa1;
        }
    }

    // ---- phase: h_512 lives in registers (2 features/lane) ----
    {
        const int f = 16 * c + 4 * q + 2 * p;
        float ph = fmaf(h2[0], Wp[f], h2[1] * Wp[f + 1]);
        #pragma unroll
        for (int m = 2; m < 64; m <<= 1)
            ph += __shfl_xor(ph, m, 64);
        if (lane < 2) out[B_TOT + b0s + lane] = ph + bp[0];   // planar imag
    }
}

extern "C" void kernel_launch(void* const* d_in, const int* in_sizes, int n_in,
                              void* d_out, int out_size, void* d_ws, size_t ws_size,
                              hipStream_t stream) {
    const int*   s  = (const int*)  d_in[0];
    const float* W0 = (const float*)d_in[1];
    const float* b0 = (const float*)d_in[2];
    const float* Wi = (const float*)d_in[3];
    const float* Wh = (const float*)d_in[4];
    const float* bh = (const float*)d_in[5];
    const float* Wa = (const float*)d_in[6];
    const float* ba = (const float*)d_in[7];
    const float* Wp = (const float*)d_in[8];
    const float* bp = (const float*)d_in[9];
    float* out = (float*)d_out;

    dim3 grid(B_TOT / 8);    // 256 blocks x 4 independent waves = 1024 waves,
    dim3 block(256);         // 1 wave/SIMD, 2 samples/wave, zero barriers
    lstm_v17_kernel<<<grid, block, 0, stream>>>(s, W0, b0, Wi, Wh, bh,
                                                Wa, ba, Wp, bp, out);
}

// Round 5
// 303.684 us; speedup vs baseline: 2.6841x; 2.6841x over previous
//
#include <hip/hip_runtime.h>
#include <math.h>

typedef _Float16 f16x8 __attribute__((ext_vector_type(8)));
typedef float    f32x4 __attribute__((ext_vector_type(4)));
typedef _Float16 f16x2 __attribute__((ext_vector_type(2)));
typedef __fp16   fp16x2 __attribute__((ext_vector_type(2)));

#define B_TOT 2048
#define LSEQ  512
#define NS    4            // samples per block; 512 blocks -> 2 independent
                           // chains per CU (separate barriers!)
#define LOG2E 1.44269504088896f
#define LN2   0.69314718055995f

#define MFMA16(A, B, C) __builtin_amdgcn_mfma_f32_16x16x32_f16((A), (B), (C), 0, 0, 0)

__global__ __launch_bounds__(256, 2)
void lstm_v18_kernel(const int* __restrict__ s,
                     const float* __restrict__ W0, const float* __restrict__ b0,
                     const float* __restrict__ Wi, const float* __restrict__ Wh,
                     const float* __restrict__ bh, const float* __restrict__ Wa,
                     const float* __restrict__ ba, const float* __restrict__ Wp,
                     const float* __restrict__ bp, float* __restrict__ out)
{
    const int tid  = threadIdx.x;
    const int w    = tid >> 6;     // wave 0..3: feature block 16w..16w+15 (all 4 gates)
    const int lane = tid & 63;
    const int n    = lane & 15;    // MFMA column; sample = n&3, 4 col-copies
    const int q    = lane >> 4;
    const int ns   = n & 3;        // sample index
    const int cp   = n >> 2;       // copy 0..3 -> acc row r = cp
    const int b0s  = blockIdx.x * NS;

    // h layout: b16 slot 64*ns + f (f = feature 0..63). Lane owns 1 cell:
    // sample ns, feature f = 16w + 4q + cp -> one ds_write_b16.
    // Read: b128 at dword 32*ns + 4q (+16): 4 lanes/addr broadcast, free.
    __shared__ __align__(16) unsigned int HhD[2][128];  //  1 KB
    __shared__ unsigned char  TOKW[LSEQ + 2];           //  0.5 KB (4-bit masks)
    __shared__ unsigned char  SRAW[NS][LSEQ];           //  2 KB
    __shared__ _Float16 DBUF[LSEQ][NS];                 //  4 KB
    __shared__ float PART[64][NS];                      //  1 KB

    // ---- stage tokens (coalesced in t) ----
    for (int i = tid; i < NS * LSEQ; i += 256)
        SRAW[i >> 9][i & 511] = (unsigned char)s[(b0s + (i >> 9)) * LSEQ + (i & 511)];
    __syncthreads();
    for (int u = tid; u <= LSEQ; u += 256) {
        unsigned int mask = 0;
        if (u >= 1) {
            #pragma unroll
            for (int m = 0; m < NS; ++m)
                mask |= ((unsigned int)SRAW[m][u - 1]) << m;
        }
        TOKW[u] = (unsigned char)mask;
    }

    // ---- A-frags: scaled Wh^T (A row m = n = feature within block) ----
    f16x8 awh[4][2];
    #pragma unroll
    for (int g = 0; g < 4; ++g) {
        const float sc  = (g == 2) ? (2.0f * LOG2E) : (-LOG2E);
        const int   col = 64 * g + 16 * w + n;
        #pragma unroll
        for (int c = 0; c < 2; ++c)
            #pragma unroll
            for (int j = 0; j < 8; ++j)
                awh[g][c][j] = (_Float16)(Wh[(32 * c + 8 * q + j) * 256 + col] * sc);
    }

    // ---- d-GEMM A-frag: row 0 = Wa[:,1]-Wa[:,0] ----
    f16x8 awd[2];
    #pragma unroll
    for (int c = 0; c < 2; ++c)
        #pragma unroll
        for (int j = 0; j < 8; ++j) {
            int k = 32 * c + 8 * q + j;
            awd[c][j] = (_Float16)((n == 0) ? (Wa[2 * k + 1] - Wa[2 * k]) : 0.0f);
        }
    const float dba = ba[1] - ba[0];

    // ---- p0/dp (scaled), full 4 rows per lane (MFMA C operand) ----
    f32x4 p0q[4], dpq[4];
    {
        float a0[4][4], a1[4][4];
        #pragma unroll
        for (int g = 0; g < 4; ++g)
            #pragma unroll
            for (int r = 0; r < 4; ++r) {
                float bb = bh[64 * g + 16 * w + 4 * q + r];
                a0[g][r] = bb; a1[g][r] = bb;
            }
        for (int f = 0; f < 64; ++f) {
            float wb0 = W0[f]      + b0[f];
            float wb1 = W0[64 + f] + b0[f];
            #pragma unroll
            for (int g = 0; g < 4; ++g) {
                const float4 wi4 = *(const float4*)&Wi[f * 256 + 64 * g + 16 * w + 4 * q];
                #pragma unroll
                for (int r = 0; r < 4; ++r) {
                    float wi = (&wi4.x)[r];
                    a0[g][r] = fmaf(wb0, wi, a0[g][r]);
                    a1[g][r] = fmaf(wb1, wi, a1[g][r]);
                }
            }
        }
        #pragma unroll
        for (int g = 0; g < 4; ++g) {
            const float sc = (g == 2) ? (2.0f * LOG2E) : (-LOG2E);
            #pragma unroll
            for (int r = 0; r < 4; ++r) {
                p0q[g][r] = a0[g][r] * sc;
                dpq[g][r] = (a1[g][r] - a0[g][r]) * sc;
            }
        }
    }

    __syncthreads();   // TOKW ready

    // ---- loop-invariant LDS addresses ----
    const int wIdx = 64 * ns + 16 * w + 4 * q + cp;     // b16 slot for h publish
    const int rAddr = 32 * ns + 4 * q;                  // dword base of B-frag

    // ---- state: 1 cell per lane ----
    float h1 = 0.f, c1 = 0.f;
    f32x4 ci[4];
    #pragma unroll
    for (int g = 0; g < 4; ++g) ci[g] = p0q[g];

    float dpend = 0.0f;
    int   tpend = -1;

    #pragma unroll 4
    for (int v = 0; v <= LSEQ; ++v) {
        const int p = v & 1;
        unsigned int* __restrict__ hb = &HhD[p][0];

        // publish h_{v-1}: one ds_write_b16 (head of the serial chain -> first)
        ((_Float16*)hb)[wIdx] = (_Float16)h1;
        __syncthreads();

        // flush last rotation's d-result (deadline = post-loop barrier)
        if (tpend >= 0) {
            if (lane < NS) DBUF[tpend][lane] = (_Float16)dpend;
            tpend = -1;
        }

        // B-frags: two ds_read_b128 (4 col-copies broadcast same sample)
        uint4 r0 = *(const uint4*)&hb[rAddr];
        uint4 r1 = *(const uint4*)&hb[rAddr + 16];
        const f16x8 bf0 = __builtin_bit_cast(f16x8, r0);
        const f16x8 bf1 = __builtin_bit_cast(f16x8, r1);

        const unsigned int tokm_next = (v < LSEQ) ? (unsigned int)TOKW[v + 1] : 0u;

        // gates GEMM
        f32x4 acc0 = ci[0], acc1 = ci[1], acc2 = ci[2], acc3 = ci[3];
        acc0 = MFMA16(awh[0][0], bf0, acc0);
        acc1 = MFMA16(awh[1][0], bf0, acc1);
        acc2 = MFMA16(awh[2][0], bf0, acc2);
        acc3 = MFMA16(awh[3][0], bf0, acc3);
        acc0 = MFMA16(awh[0][1], bf1, acc0);
        acc1 = MFMA16(awh[1][1], bf1, acc1);
        acc2 = MFMA16(awh[2][1], bf1, acc2);
        acc3 = MFMA16(awh[3][1], bf1, acc3);

        // rotating wave: raw logit-diff for step v-1 (pipelines behind gate MFMAs)
        if (v >= 1 && w == (v & 3)) {
            f32x4 da = (f32x4){dba, dba, dba, dba};
            da = MFMA16(awd[0], bf0, da);
            da = MFMA16(awd[1], bf1, da);
            dpend = da[0];
            tpend = v - 1;
        }

        // C-init for next iter: v_pk_fma_f32
        const float sel = (float)((tokm_next >> ns) & 1u);
        const f32x4 sel4 = {sel, sel, sel, sel};
        #pragma unroll
        for (int g = 0; g < 4; ++g)
            ci[g] = dpq[g] * sel4 + p0q[g];

        // select this lane's 4 gate values: row r = cp of each acc
        const bool s1 = (cp & 1) != 0;
        const bool s2 = (cp & 2) != 0;
        float gi = s2 ? (s1 ? acc0[3] : acc0[2]) : (s1 ? acc0[1] : acc0[0]);
        float gf = s2 ? (s1 ? acc1[3] : acc1[2]) : (s1 ? acc1[1] : acc1[0]);
        float gg = s2 ? (s1 ? acc2[3] : acc2[2]) : (s1 ? acc2[1] : acc2[0]);
        float go = s2 ? (s1 ? acc3[3] : acc3[2]) : (s1 ? acc3[1] : acc3[0]);

        // activation: 5 exp2 + 2 rcp (single cell)
        {
            float ei = __builtin_amdgcn_exp2f(gi);                // e^{-i}
            float ef = __builtin_amdgcn_exp2f(gf);                // e^{-f}
            float eg = __builtin_amdgcn_exp2f(gg);                // e^{2g}
            float eo = __builtin_amdgcn_exp2f(go);                // e^{-o}
            float P  = (1.0f + ei) * (eg + 1.0f);
            float F  = 1.0f + ef;
            float R2 = __builtin_amdgcn_rcpf(P * F);
            float cn = fmaf(c1 * P, R2, (eg - 1.0f) * F * R2);
            c1 = cn;
            float ec = __builtin_amdgcn_exp2f(fminf(cn * (2.0f * LOG2E), 60.f));
            float Ro = __builtin_amdgcn_rcpf((1.0f + eo) * (ec + 1.0f));
            h1 = (ec - 1.0f) * Ro;
        }
    }

    // ---- tail: flush pending d (wave 0, t=511), publish h_512 into buffer 1 ----
    if (tpend >= 0 && lane < NS) DBUF[tpend][lane] = (_Float16)dpend;
    ((_Float16*)&HhD[1][0])[wIdx] = (_Float16)h1;
    __syncthreads();

    // ---- amp post-pass: 4 samples x 512 t, 8 t per thread ----
    {
        const int nn = tid & 3;
        const int cc = tid >> 2;             // 0..63
        float a = 0.0f;
        #pragma unroll 4
        for (int k = 0; k < 8; ++k) {
            int t = cc * 8 + k;
            float d = (float)DBUF[t][nn];
            float x = SRAW[nn][t] ? -d : d;
            float e = __builtin_amdgcn_exp2f(-fabsf(x) * LOG2E);
            a += fmaxf(x, 0.0f) + __builtin_amdgcn_logf(1.0f + e) * LN2;
        }
        PART[cc][nn] = a;
    }
    __syncthreads();

    if (tid < NS) {
        float ssum = 0.0f;
        #pragma unroll
        for (int c = 0; c < 64; ++c) ssum += PART[c][tid];
        out[b0s + tid] = -0.5f * ssum;              // planar real
    }

    // ---- phase: wave 0; lane (n,q): sample q, features 4n..4n+3 ----
    if (w == 0) {
        unsigned int ua = HhD[1][32 * q + 2 * n];
        unsigned int ub = HhD[1][32 * q + 2 * n + 1];
        f16x2 ha = __builtin_bit_cast(f16x2, ua);
        f16x2 hc = __builtin_bit_cast(f16x2, ub);
        float ph = fmaf((float)ha[0], Wp[4 * n],
                   fmaf((float)ha[1], Wp[4 * n + 1],
                   fmaf((float)hc[0], Wp[4 * n + 2],
                        (float)hc[1] * Wp[4 * n + 3])));
        ph += __shfl_xor(ph, 1, 64);
        ph += __shfl_xor(ph, 2, 64);
        ph += __shfl_xor(ph, 4, 64);
        ph += __shfl_xor(ph, 8, 64);
        if (n == 0) out[B_TOT + b0s + q] = ph + bp[0];   // planar imag
    }
}

extern "C" void kernel_launch(void* const* d_in, const int* in_sizes, int n_in,
                              void* d_out, int out_size, void* d_ws, size_t ws_size,
                              hipStream_t stream) {
    const int*   s  = (const int*)  d_in[0];
    const float* W0 = (const float*)d_in[1];
    const float* b0 = (const float*)d_in[2];
    const float* Wi = (const float*)d_in[3];
    const float* Wh = (const float*)d_in[4];
    const float* bh = (const float*)d_in[5];
    const float* Wa = (const float*)d_in[6];
    const float* ba = (const float*)d_in[7];
    const float* Wp = (const float*)d_in[8];
    const float* bp = (const float*)d_in[9];
    float* out = (float*)d_out;

    dim3 grid(B_TOT / NS);   // 512 WGs x 4 waves: 2 chains/CU with INDEPENDENT
    dim3 block(256);         // barriers; 1 cell/lane (cols duplicated 4x)
    lstm_v18_kernel<<<grid, block, 0, stream>>>(s, W0, b0, Wi, Wh, bh,
                                                Wa, ba, Wp, bp, out);
}